// Round 1
// baseline (272.455 us; speedup 1.0000x reference)
//
#include <hip/hip_runtime.h>
#include <hip/hip_bf16.h>

using short8  = __attribute__((ext_vector_type(8))) short;
using floatx4 = __attribute__((ext_vector_type(4))) float;

#define CC 192
#define CN 4096
#define NHEAD 6
#define DHEAD 32

// ---------------- kernel 0: rope cos/sin table ----------------
// tab[n*96 + c2] = (cos(ang), sin(ang)), ang = (c2<48 ? h : w) * base^(-i/48)
__global__ void k0_table(float2* __restrict__ tab) {
    int idx = blockIdx.x * 256 + threadIdx.x;
    if (idx >= CN * 96) return;
    int n = idx / 96, c2 = idx - n * 96;
    int h = n >> 6, w = n & 63;
    int i = (c2 < 48) ? c2 : c2 - 48;
    float pos = (float)((c2 < 48) ? h : w);
    float theta = expf(-(float)i * (9.210340371976184f / 48.0f)); // ln(10000)/48
    float ang = pos * theta;
    tab[idx] = make_float2(cosf(ang), sinf(ang));
}

__global__ void k_zero(float* __restrict__ p, int n) {
    int i = blockIdx.x * 256 + threadIdx.x;
    if (i < n) p[i] = 0.f;
}

// ---------------- kernel 1: qk = x @ qk_w.T + b ; q,k = elu(..)+1 -> bf16 ----------------
// M-tile 128 rows x full N=384, K=192 in 6 steps of 32. 8 waves: 4(M) x 2(N).
#define LDSP 40  // padded LDS row stride (elements) -> 80B, cycles all 32 banks
__global__ __launch_bounds__(512)
void k1_gemm(const float* __restrict__ x, const float* __restrict__ qkw,
             const float* __restrict__ qkb,
             __hip_bfloat16* __restrict__ qws, __hip_bfloat16* __restrict__ kws)
{
    __shared__ __align__(16) __hip_bfloat16 A_lds[128 * LDSP];
    __shared__ __align__(16) __hip_bfloat16 B_lds[384 * LDSP];

    const int tid  = threadIdx.x;
    const int wid  = tid >> 6, lane = tid & 63;
    const int wm   = wid >> 1, wn = wid & 1;
    const int lrow = lane & 15;
    const int l4   = lane >> 4;
    const int lk   = l4 * 8;
    const long rowBase = (long)blockIdx.x * 128;

    floatx4 acc[2][12];
#pragma unroll
    for (int i = 0; i < 2; ++i)
#pragma unroll
        for (int j = 0; j < 12; ++j) acc[i][j] = (floatx4)0.f;

    for (int ks = 0; ks < 6; ++ks) {
        const int k0 = ks * 32;
        // stage A: 128 rows x 32 ch (f32 -> bf16), 8 per thread
        {
            int r = tid >> 2, cc = (tid & 3) * 8;
            const float* src = x + (rowBase + r) * CC + k0 + cc;
#pragma unroll
            for (int j = 0; j < 8; ++j) A_lds[r * LDSP + cc + j] = __float2bfloat16(src[j]);
        }
        // stage B: 384 cols x 32 ch of w (stored [col][k])
#pragma unroll
        for (int c3 = 0; c3 < 3; ++c3) {
            int idx = tid * 8 + c3 * 4096;
            int o = idx >> 5, cc = idx & 31;
            const float* src = qkw + o * CC + k0 + cc;
#pragma unroll
            for (int j = 0; j < 8; ++j) B_lds[o * LDSP + cc + j] = __float2bfloat16(src[j]);
        }
        __syncthreads();

        short8 a0 = *(const short8*)&A_lds[(wm * 32 + lrow) * LDSP + lk];
        short8 a1 = *(const short8*)&A_lds[(wm * 32 + 16 + lrow) * LDSP + lk];
#pragma unroll
        for (int ni = 0; ni < 12; ++ni) {
            short8 bf = *(const short8*)&B_lds[(wn * 192 + ni * 16 + lrow) * LDSP + lk];
            acc[0][ni] = __builtin_amdgcn_mfma_f32_16x16x32_bf16(a0, bf, acc[0][ni], 0, 0, 0);
            acc[1][ni] = __builtin_amdgcn_mfma_f32_16x16x32_bf16(a1, bf, acc[1][ni], 0, 0, 0);
        }
        __syncthreads();
    }

    // epilogue: +bias, elu+1, write bf16. wn==0 -> q, wn==1 -> k (wave-uniform)
    __hip_bfloat16* dstbase = wn ? kws : qws;
#pragma unroll
    for (int ni = 0; ni < 12; ++ni) {
        int col_l = ni * 16 + lrow;           // 0..191 within q or k
        float bias = qkb[wn * 192 + col_l];
#pragma unroll
        for (int mi = 0; mi < 2; ++mi) {
#pragma unroll
            for (int r = 0; r < 4; ++r) {
                int rowl = wm * 32 + mi * 16 + l4 * 4 + r;
                long rowg = rowBase + rowl;
                float v = acc[mi][ni][r] + bias;
                v = (v > 0.f) ? (v + 1.f) : expf(v);
                dstbase[rowg * CC + col_l] = __float2bfloat16(v);
            }
        }
    }
}

// ---------------- kernel 2: kv[b,hd] = (1/n) k_rope^T v ; kmean[b,hd] ----------------
// grid: chunk(8) x head(6) x b(16). 256 thr: g=tid>>5 (row in 8-group), e=tid&31.
__global__ __launch_bounds__(256)
void k2_kv(const __hip_bfloat16* __restrict__ kws, const float* __restrict__ x,
           const float2* __restrict__ tab, float* __restrict__ kv, float* __restrict__ kmean)
{
    int bid = blockIdx.x;
    int chunk = bid & 7;
    int hd = (bid >> 3) % NHEAD;
    int b = bid / (8 * NHEAD);
    int tid = threadIdx.x;
    int e = tid & 31, g = tid >> 5;
    int d4 = g * 4;

    __shared__ __align__(16) float kraw[8][32];
    __shared__ __align__(16) float kr[8][32];
    __shared__ __align__(16) float vv[8][32];

    float acc0 = 0.f, acc1 = 0.f, acc2 = 0.f, acc3 = 0.f, msum = 0.f;
    const int n0 = chunk * 512;

    for (int it = 0; it < 64; ++it) {
        int n = n0 + it * 8 + g;
        long rowg = (long)b * CN + n;
        float kval = __bfloat162float(kws[rowg * CC + hd * DHEAD + e]);
        float xval = x[rowg * CC + hd * DHEAD + e];
        __syncthreads();                    // prev-iter reads of kr/vv done
        kraw[g][e] = kval;
        vv[g][e]   = xval;
        msum += kval;
        __syncthreads();
        {   // rope on k: c2 = hd*16 + e/2
            float2 cs = tab[(long)n * 96 + hd * 16 + (e >> 1)];
            float a  = kraw[g][e & ~1];
            float bb = kraw[g][e | 1];
            kr[g][e] = (e & 1) ? (a * cs.y + bb * cs.x) : (a * cs.x - bb * cs.y);
        }
        __syncthreads();
#pragma unroll
        for (int r = 0; r < 8; ++r) {
            float4 k4 = *(const float4*)&kr[r][d4];   // broadcast within wave
            float v1 = vv[r][e];
            acc0 += k4.x * v1; acc1 += k4.y * v1; acc2 += k4.z * v1; acc3 += k4.w * v1;
        }
    }
    const float s = 1.f / 4096.f;
    float* kvb = kv + ((long)(b * NHEAD + hd) * DHEAD) * DHEAD;
    atomicAdd(&kvb[(d4 + 0) * DHEAD + e], acc0 * s);
    atomicAdd(&kvb[(d4 + 1) * DHEAD + e], acc1 * s);
    atomicAdd(&kvb[(d4 + 2) * DHEAD + e], acc2 * s);
    atomicAdd(&kvb[(d4 + 3) * DHEAD + e], acc3 * s);
    // kmean: reduce msum across g
    __syncthreads();
    kraw[g][e] = msum;
    __syncthreads();
    if (g == 0) {
        float t = 0.f;
#pragma unroll
        for (int r = 0; r < 8; ++r) t += kraw[r][e];
        atomicAdd(&kmean[(b * NHEAD + hd) * DHEAD + e], t * s);
    }
}

// ---------------- kernel 3: out = (q_rope @ kv) * z + lepe ----------------
// block per (b, h-row); 192 threads = channels; loop 64 w positions.
__global__ __launch_bounds__(192)
void k3_out(const __hip_bfloat16* __restrict__ qws, const float* __restrict__ x,
            const float2* __restrict__ tab, const float* __restrict__ kv,
            const float* __restrict__ kmean, const float* __restrict__ lw,
            const float* __restrict__ lb, float* __restrict__ out)
{
    int bid = blockIdx.x;
    int b = bid >> 6, h = bid & 63;
    int c = threadIdx.x;
    int hd = c >> 5, e = c & 31;

    __shared__ __align__(16) float kv_lds[NHEAD * DHEAD * DHEAD]; // 24KB
    __shared__ float km_lds[CC];
    __shared__ float q_lds[CC];
    __shared__ float qr_lds[CC];
    __shared__ float z_lds[NHEAD];

    const float* kvsrc = kv + (long)b * NHEAD * DHEAD * DHEAD;
    for (int i = c; i < NHEAD * DHEAD * DHEAD; i += 192) kv_lds[i] = kvsrc[i];
    km_lds[c] = kmean[b * CC + c];
    float w9[9];
#pragma unroll
    for (int j = 0; j < 9; ++j) w9[j] = lw[c * 9 + j];
    float lbv = lb[c];
    __syncthreads();

    for (int w = 0; w < 64; ++w) {
        int n = h * 64 + w;
        long rowg = (long)b * CN + n;
        q_lds[c] = __bfloat162float(qws[rowg * CC + c]);
        __syncthreads();
        // z = 1/(q . kmean + eps) per head (32-lane butterfly)
        float p = q_lds[c] * km_lds[c];
#pragma unroll
        for (int off = 16; off >= 1; off >>= 1) p += __shfl_xor(p, off);
        if (e == 0) z_lds[hd] = 1.f / (p + 1e-6f);
        // rope on q
        float2 cs = tab[(long)n * 96 + (c >> 1)];
        float a0 = q_lds[c & ~1];
        float a1 = q_lds[c | 1];
        float qr = (c & 1) ? (a0 * cs.y + a1 * cs.x) : (a0 * cs.x - a1 * cs.y);
        __syncthreads();                 // z_lds visible, q_lds reads done
        qr_lds[c] = qr;
        __syncthreads();
        // matvec over d
        float acc = 0.f;
        const float* kvh = &kv_lds[hd * DHEAD * DHEAD];
        const float* qrh = &qr_lds[hd * DHEAD];
#pragma unroll
        for (int d = 0; d < DHEAD; ++d) acc += qrh[d] * kvh[d * DHEAD + e];
        // lepe: depthwise 3x3 SAME on x
        float le = lbv;
#pragma unroll
        for (int dy = 0; dy < 3; ++dy) {
            int hy = h + dy - 1;
            if (hy < 0 || hy > 63) continue;
#pragma unroll
            for (int dx = 0; dx < 3; ++dx) {
                int wx = w + dx - 1;
                if (wx < 0 || wx > 63) continue;
                le += x[(((long)b * 64 + hy) * 64 + wx) * CC + c] * w9[dy * 3 + dx];
            }
        }
        out[rowg * CC + c] = acc * z_lds[hd] + le;
        __syncthreads();                 // qr_lds/z_lds reads done before next iter
    }
}

extern "C" void kernel_launch(void* const* d_in, const int* in_sizes, int n_in,
                              void* d_out, int out_size, void* d_ws, size_t ws_size,
                              hipStream_t stream)
{
    const float* x   = (const float*)d_in[0];
    const float* qkw = (const float*)d_in[1];
    const float* qkb = (const float*)d_in[2];
    const float* lw  = (const float*)d_in[3];
    const float* lb  = (const float*)d_in[4];
    float* out = (float*)d_out;

    char* ws = (char*)d_ws;
    float2* tab = (float2*)ws;                 ws += (size_t)CN * 96 * sizeof(float2);
    __hip_bfloat16* qws = (__hip_bfloat16*)ws; ws += (size_t)16 * CN * CC * 2;
    __hip_bfloat16* kws = (__hip_bfloat16*)ws; ws += (size_t)16 * CN * CC * 2;
    float* kv = (float*)ws;                    ws += (size_t)16 * NHEAD * DHEAD * DHEAD * 4;
    float* km = (float*)ws;                    ws += (size_t)16 * NHEAD * DHEAD * 4;

    const int nzero = 16 * NHEAD * DHEAD * DHEAD + 16 * NHEAD * DHEAD; // kv+km contiguous
    k_zero<<<(nzero + 255) / 256, 256, 0, stream>>>(kv, nzero);
    k0_table<<<(CN * 96 + 255) / 256, 256, 0, stream>>>(tab);
    k1_gemm<<<512, 512, 0, stream>>>(x, qkw, qkb, qws, kws);
    k2_kv<<<16 * NHEAD * 8, 256, 0, stream>>>(kws, x, tab, kv, km);
    k3_out<<<16 * 64, 192, 0, stream>>>(qws, x, tab, kv, km, lw, lb, out);
}

// Round 2
// 137.397 us; speedup vs baseline: 1.9830x; 1.9830x over previous
//
#include <hip/hip_runtime.h>
#include <hip/hip_bf16.h>

using short8  = __attribute__((ext_vector_type(8))) short;
using floatx4 = __attribute__((ext_vector_type(4))) float;

#define CC 192
#define CN 4096
#define NHEAD 6
#define DHEAD 32

__device__ __forceinline__ float bf2f(short s) {
    return __uint_as_float(((unsigned)(unsigned short)s) << 16);
}
__device__ __forceinline__ short f2bf(float f) {
    __hip_bfloat16 h = __float2bfloat16(f);
    return *(short*)&h;
}

// ---------------- kernel 0: rope cos/sin table ----------------
__global__ void k0_table(float2* __restrict__ tab) {
    int idx = blockIdx.x * 256 + threadIdx.x;
    if (idx >= CN * 96) return;
    int n = idx / 96, c2 = idx - n * 96;
    int h = n >> 6, w = n & 63;
    int i = (c2 < 48) ? c2 : c2 - 48;
    float pos = (float)((c2 < 48) ? h : w);
    float theta = expf(-(float)i * (9.210340371976184f / 48.0f)); // ln(10000)/48
    float ang = pos * theta;
    tab[idx] = make_float2(cosf(ang), sinf(ang));
}

__global__ void k_zero(float* __restrict__ p, int n) {
    int i = blockIdx.x * 256 + threadIdx.x;
    if (i < n) p[i] = 0.f;
}

// ---------------- kernel 1: qk = x @ qk_w.T + b ; q,k = elu(..)+1 -> bf16 ----------------
#define LDSP 40
__global__ __launch_bounds__(512)
void k1_gemm(const float* __restrict__ x, const float* __restrict__ qkw,
             const float* __restrict__ qkb,
             __hip_bfloat16* __restrict__ qws, __hip_bfloat16* __restrict__ kws)
{
    __shared__ __align__(16) __hip_bfloat16 A_lds[128 * LDSP];
    __shared__ __align__(16) __hip_bfloat16 B_lds[384 * LDSP];

    const int tid  = threadIdx.x;
    const int wid  = tid >> 6, lane = tid & 63;
    const int wm   = wid >> 1, wn = wid & 1;
    const int lrow = lane & 15;
    const int l4   = lane >> 4;
    const int lk   = l4 * 8;
    const long rowBase = (long)blockIdx.x * 128;

    floatx4 acc[2][12];
#pragma unroll
    for (int i = 0; i < 2; ++i)
#pragma unroll
        for (int j = 0; j < 12; ++j) acc[i][j] = (floatx4)0.f;

    for (int ks = 0; ks < 6; ++ks) {
        const int k0 = ks * 32;
        {
            int r = tid >> 2, cc = (tid & 3) * 8;
            const float* src = x + (rowBase + r) * CC + k0 + cc;
#pragma unroll
            for (int j = 0; j < 8; ++j) A_lds[r * LDSP + cc + j] = __float2bfloat16(src[j]);
        }
#pragma unroll
        for (int c3 = 0; c3 < 3; ++c3) {
            int idx = tid * 8 + c3 * 4096;
            int o = idx >> 5, cc = idx & 31;
            const float* src = qkw + o * CC + k0 + cc;
#pragma unroll
            for (int j = 0; j < 8; ++j) B_lds[o * LDSP + cc + j] = __float2bfloat16(src[j]);
        }
        __syncthreads();

        short8 a0 = *(const short8*)&A_lds[(wm * 32 + lrow) * LDSP + lk];
        short8 a1 = *(const short8*)&A_lds[(wm * 32 + 16 + lrow) * LDSP + lk];
#pragma unroll
        for (int ni = 0; ni < 12; ++ni) {
            short8 bf = *(const short8*)&B_lds[(wn * 192 + ni * 16 + lrow) * LDSP + lk];
            acc[0][ni] = __builtin_amdgcn_mfma_f32_16x16x32_bf16(a0, bf, acc[0][ni], 0, 0, 0);
            acc[1][ni] = __builtin_amdgcn_mfma_f32_16x16x32_bf16(a1, bf, acc[1][ni], 0, 0, 0);
        }
        __syncthreads();
    }

    __hip_bfloat16* dstbase = wn ? kws : qws;
#pragma unroll
    for (int ni = 0; ni < 12; ++ni) {
        int col_l = ni * 16 + lrow;
        float bias = qkb[wn * 192 + col_l];
#pragma unroll
        for (int mi = 0; mi < 2; ++mi) {
#pragma unroll
            for (int r = 0; r < 4; ++r) {
                int rowl = wm * 32 + mi * 16 + l4 * 4 + r;
                long rowg = rowBase + rowl;
                float v = acc[mi][ni][r] + bias;
                v = (v > 0.f) ? (v + 1.f) : expf(v);
                dstbase[rowg * CC + col_l] = __float2bfloat16(v);
            }
        }
    }
}

// ---------------- kernel 2: kv[b,hd] = (1/4096) k_rope^T v ; kmean ----------------
// grid: chunk(8) x head(6) x b(16). 256 thr. 4 batches of 128 rows, 2 barriers each.
__global__ __launch_bounds__(256)
void k2_kv(const __hip_bfloat16* __restrict__ kws, const float* __restrict__ x,
           const float2* __restrict__ tab, float* __restrict__ kv, float* __restrict__ kmean)
{
    int bid = blockIdx.x;
    int chunk = bid & 7;
    int hd = (bid >> 3) % NHEAD;
    int b = bid / (8 * NHEAD);
    int tid = threadIdx.x;

    __shared__ __align__(16) float kr_s[128][36];
    __shared__ __align__(16) float v_s[128][36];
    __shared__ float km_s[32];

    if (tid < 32) km_s[tid] = 0.f;

    const int e_g = tid & 31, g = tid >> 5, d4 = g * 4;
    const int krow = tid >> 2, kq = tid & 3;   // k-load: 64 rows/pass
    const int vrow = tid >> 3, vo = tid & 7;   // v-load: 32 rows/pass

    float acc0 = 0.f, acc1 = 0.f, acc2 = 0.f, acc3 = 0.f;
    float msum[8];
#pragma unroll
    for (int j = 0; j < 8; ++j) msum[j] = 0.f;

    const int n0 = chunk * 512;
    const long rb = (long)b * CN;

    for (int batch = 0; batch < 4; ++batch) {
        const int nb = n0 + batch * 128;
        if (batch) __syncthreads();   // compute-phase reads done
        // --- load+rope k: 2 passes of 64 rows ---
#pragma unroll
        for (int p = 0; p < 2; ++p) {
            int r = p * 64 + krow;
            int n = nb + r;
            short8 kq8 = *(const short8*)&kws[(rb + n) * CC + hd * DHEAD + kq * 8];
            float kf[8];
#pragma unroll
            for (int j = 0; j < 8; ++j) { kf[j] = bf2f(kq8[j]); msum[j] += kf[j]; }
            const float4* tp = (const float4*)&tab[(long)n * 96 + hd * 16 + kq * 4];
            float4 t0 = tp[0], t1 = tp[1];
            float4 r0, r1;
            r0.x = kf[0]*t0.x - kf[1]*t0.y;  r0.y = kf[0]*t0.y + kf[1]*t0.x;
            r0.z = kf[2]*t0.z - kf[3]*t0.w;  r0.w = kf[2]*t0.w + kf[3]*t0.z;
            r1.x = kf[4]*t1.x - kf[5]*t1.y;  r1.y = kf[4]*t1.y + kf[5]*t1.x;
            r1.z = kf[6]*t1.z - kf[7]*t1.w;  r1.w = kf[6]*t1.w + kf[7]*t1.z;
            *(float4*)&kr_s[r][kq * 8]     = r0;
            *(float4*)&kr_s[r][kq * 8 + 4] = r1;
        }
        // --- load v: 4 passes of 32 rows ---
#pragma unroll
        for (int p = 0; p < 4; ++p) {
            int r = p * 32 + vrow;
            float4 vv = *(const float4*)&x[(rb + nb + r) * CC + hd * DHEAD + vo * 4];
            *(float4*)&v_s[r][vo * 4] = vv;
        }
        __syncthreads();
        // --- rank-4 accumulate over 128 rows, no barriers ---
#pragma unroll 8
        for (int r = 0; r < 128; ++r) {
            float4 k4 = *(const float4*)&kr_s[r][d4];
            float v1 = v_s[r][e_g];
            acc0 += k4.x * v1; acc1 += k4.y * v1; acc2 += k4.z * v1; acc3 += k4.w * v1;
        }
    }
    const float s = 1.f / 4096.f;
    float* kvb = kv + (long)(b * NHEAD + hd) * DHEAD * DHEAD;
    atomicAdd(&kvb[(d4 + 0) * DHEAD + e_g], acc0 * s);
    atomicAdd(&kvb[(d4 + 1) * DHEAD + e_g], acc1 * s);
    atomicAdd(&kvb[(d4 + 2) * DHEAD + e_g], acc2 * s);
    atomicAdd(&kvb[(d4 + 3) * DHEAD + e_g], acc3 * s);
    __syncthreads();
#pragma unroll
    for (int j = 0; j < 8; ++j) atomicAdd(&km_s[kq * 8 + j], msum[j]);
    __syncthreads();
    if (tid < 32) atomicAdd(&kmean[(b * NHEAD + hd) * DHEAD + tid], km_s[tid] * s);
}

// ---------------- kernel 3: out = (q_rope @ kv) * z + lepe ----------------
// block per (b,h): 256 thr. Phase1: parallel load/rope/z (no barriers).
// Phase2: MFMA matvec + fused LePE epilogue. 2 barriers total.
__global__ __launch_bounds__(256)
void k3_out(const __hip_bfloat16* __restrict__ qws, const float* __restrict__ x,
            const float2* __restrict__ tab, const float* __restrict__ kv,
            const float* __restrict__ kmean, const float* __restrict__ lw,
            const float* __restrict__ lb, float* __restrict__ out)
{
    int bid = blockIdx.x;
    int b = bid >> 6, h = bid & 63;
    int tid = threadIdx.x;
    int wave = tid >> 6, lane = tid & 63, lrow = lane & 15, l4 = lane >> 4;

    __shared__ __align__(16) __hip_bfloat16 qr_lds[64][200];       // padded
    __shared__ __align__(16) __hip_bfloat16 kvt[NHEAD][32][36];    // [hd][e][d]
    __shared__ float km_lds[CC];
    __shared__ float lw_lds[CC * 9];
    __shared__ float lb_lds[CC];
    __shared__ float zden[64][8];

    const long nbase = (long)b * CN + h * 64;

    // stage kv (transposed, bf16), kmean, lepe weights
    const float* kvsrc = kv + (long)b * NHEAD * DHEAD * DHEAD;
    for (int i = tid; i < NHEAD * DHEAD * DHEAD; i += 256) {
        int hd = i >> 10, d = (i >> 5) & 31, e = i & 31;
        kvt[hd][e][d] = __float2bfloat16(kvsrc[i]);
    }
    if (tid < CC) { km_lds[tid] = kmean[b * CC + tid]; lb_lds[tid] = lb[tid]; }
    for (int i = tid; i < CC * 9; i += 256) lw_lds[i] = lw[i];

    // phase 1: q load (fully coalesced), rope, z partial dot
#pragma unroll
    for (int it = 0; it < 6; ++it) {
        int slot = it * 256 + tid;          // 0..1535
        int w = slot / 24;
        int sub = slot - w * 24;
        int c0 = sub * 8;
        short8 qv = *(const short8*)&qws[(nbase + w) * CC + c0];
        float q[8];
#pragma unroll
        for (int j = 0; j < 8; ++j) q[j] = bf2f(qv[j]);
        // z partial: dot(q, kmean) over these 8 channels, reduce across 4 lanes
        float p = 0.f;
#pragma unroll
        for (int j = 0; j < 8; ++j) p += q[j] * km_lds[c0 + j];
        p += __shfl_xor(p, 1);
        p += __shfl_xor(p, 2);
        if ((sub & 3) == 0) zden[w][sub >> 2] = p;
        // rope
        int n = h * 64 + w;
        const float4* tp = (const float4*)&tab[(long)n * 96 + (c0 >> 1)];
        float4 t0 = tp[0], t1 = tp[1];
        short8 qr;
        qr[0] = f2bf(q[0]*t0.x - q[1]*t0.y);  qr[1] = f2bf(q[0]*t0.y + q[1]*t0.x);
        qr[2] = f2bf(q[2]*t0.z - q[3]*t0.w);  qr[3] = f2bf(q[2]*t0.w + q[3]*t0.z);
        qr[4] = f2bf(q[4]*t1.x - q[5]*t1.y);  qr[5] = f2bf(q[4]*t1.y + q[5]*t1.x);
        qr[6] = f2bf(q[6]*t1.z - q[7]*t1.w);  qr[7] = f2bf(q[6]*t1.w + q[7]*t1.z);
        *(short8*)&qr_lds[w][c0] = qr;
    }
    __syncthreads();

    // phase 2: MFMA matvec (rows = 16 w's per wave) + LePE epilogue
    const int rt = wave;                    // row tile 0..3
    const int wbase = rt * 16 + l4 * 4;
#pragma unroll
    for (int hd = 0; hd < NHEAD; ++hd) {
        short8 a = *(const short8*)&qr_lds[rt * 16 + lrow][hd * 32 + l4 * 8];
#pragma unroll
        for (int nt = 0; nt < 2; ++nt) {
            short8 bfr = *(const short8*)&kvt[hd][nt * 16 + lrow][l4 * 8];
            floatx4 acc = __builtin_amdgcn_mfma_f32_16x16x32_bf16(a, bfr, (floatx4)0.f, 0, 0, 0);
            int col = hd * 32 + nt * 16 + lrow;
            float w9[9];
#pragma unroll
            for (int j = 0; j < 9; ++j) w9[j] = lw_lds[col * 9 + j];
            float le[4];
#pragma unroll
            for (int r = 0; r < 4; ++r) le[r] = lb_lds[col];
#pragma unroll
            for (int dy = 0; dy < 3; ++dy) {
                int hy = h + dy - 1;
                if (hy < 0 || hy > 63) continue;
                const float* xrow = x + (((long)b * 64 + hy) * 64) * CC + col;
                float xv[6];
#pragma unroll
                for (int t = 0; t < 6; ++t) {
                    int wx = wbase - 1 + t;
                    xv[t] = (wx >= 0 && wx < 64) ? xrow[(long)wx * CC] : 0.f;
                }
#pragma unroll
                for (int r = 0; r < 4; ++r)
                    le[r] += xv[r] * w9[dy * 3] + xv[r + 1] * w9[dy * 3 + 1] + xv[r + 2] * w9[dy * 3 + 2];
            }
#pragma unroll
            for (int r = 0; r < 4; ++r) {
                int w = wbase + r;
                float z = 1.f / (zden[w][hd] + 1e-6f);
                out[(nbase + w) * CC + col] = acc[r] * z + le[r];
            }
        }
    }
}

extern "C" void kernel_launch(void* const* d_in, const int* in_sizes, int n_in,
                              void* d_out, int out_size, void* d_ws, size_t ws_size,
                              hipStream_t stream)
{
    const float* x   = (const float*)d_in[0];
    const float* qkw = (const float*)d_in[1];
    const float* qkb = (const float*)d_in[2];
    const float* lw  = (const float*)d_in[3];
    const float* lb  = (const float*)d_in[4];
    float* out = (float*)d_out;

    char* ws = (char*)d_ws;
    float2* tab = (float2*)ws;                 ws += (size_t)CN * 96 * sizeof(float2);
    __hip_bfloat16* qws = (__hip_bfloat16*)ws; ws += (size_t)16 * CN * CC * 2;
    __hip_bfloat16* kws = (__hip_bfloat16*)ws; ws += (size_t)16 * CN * CC * 2;
    float* kv = (float*)ws;                    ws += (size_t)16 * NHEAD * DHEAD * DHEAD * 4;
    float* km = (float*)ws;                    ws += (size_t)16 * NHEAD * DHEAD * 4;

    const int nzero = 16 * NHEAD * DHEAD * DHEAD + 16 * NHEAD * DHEAD;
    k_zero<<<(nzero + 255) / 256, 256, 0, stream>>>(kv, nzero);
    k0_table<<<(CN * 96 + 255) / 256, 256, 0, stream>>>(tab);
    k1_gemm<<<512, 512, 0, stream>>>(x, qkw, qkb, qws, kws);
    k2_kv<<<16 * NHEAD * 8, 256, 0, stream>>>(kws, x, tab, kv, km);
    k3_out<<<16 * 64, 192 + 64, 0, stream>>>(qws, x, tab, kv, km, lw, lb, out);
}